// Round 9
// baseline (588.256 us; speedup 1.0000x reference)
//
#include <hip/hip_runtime.h>

// UniversalGRU: 2-layer GRU (B=2048, T=512, D=1, H=64) + FC(64->1).
// R16: K-STEP INTERVAL design. Lesson from R8-R15: every per-step
// block-wide convergence costs ~900-1400 cyc of sync+latency that no
// co-resident work fills (R12 lockstep 1390; R13 flags 2100; R15 G=2
// 2400). The recurrence is batch-parallel and the only cross-wave dep
// (hA: L0->L1) tolerates skew -- so barrier every KS=8 steps:
//  - wave 0 (L0): owns ALL of Whh0 (24 frags, 96 VGPR); hA recurrence
//    fully lane-local in registers (same closure as R10, HW-verified).
//    x-term AND biases folded into one extra MFMA per gate: B-operand
//    BX = [x, 1.0, 0...] in k-slots 0/1 -> kills 112 const VGPRs.
//    Publishes hA(t) quarters (R12's proven ui2 format) to a 16-slot
//    LDS ring. No LDS reads except prefetchable xbuf.
//  - wave 1 (L1): owns Whh1 resident (96 VGPR); hB recurrence register-
//    local, publishes NOTHING. Streams Wih1 from an LDS stash per step
//    (24x ds_read_b128, loop-invariant). Consumes hA ring chunk k-1
//    while L0 produces chunk k (disjoint ring halves).
// 65 barriers total (vs 513). Both waves issue-bound (~850/1020 cyc per
// step) on separate SIMDs. 128 blocks x 128 threads, 16 rows/block.

#define T_LEN 512
#define KS    8
#define NI    (T_LEN / KS)      // 64 chunks
#define RING  (2 * KS)          // 16 slots
#define XPAD  513
#define LOG2E 1.44269504088896f

typedef float          f32x4 __attribute__((ext_vector_type(4)));
typedef __bf16         bf16x8 __attribute__((ext_vector_type(8)));
typedef unsigned short us8   __attribute__((ext_vector_type(8)));
typedef unsigned int   ui4   __attribute__((ext_vector_type(4)));
typedef unsigned int   ui2   __attribute__((ext_vector_type(2)));
typedef unsigned short ushort_t;

__device__ __forceinline__ float bf2f(ushort_t b){
    unsigned int u = ((unsigned int)b) << 16;
    return __uint_as_float(u);
}
__device__ __forceinline__ ushort_t f2bf(float f){
    unsigned int u = __float_as_uint(f);
    u = (u + 0x7FFFu + ((u >> 16) & 1u)) >> 16;   // RNE
    return (ushort_t)u;
}
__device__ __forceinline__ float ld_any(const void* p, int i, bool f32){
    return f32 ? ((const float*)p)[i] : bf2f(((const ushort_t*)p)[i]);
}
__device__ __forceinline__ float exp2_fast(float x){
#if __has_builtin(__builtin_amdgcn_exp2f)
    return __builtin_amdgcn_exp2f(x);          // v_exp_f32 (2^x)
#else
    return __expf(0.6931471805599453f * x);
#endif
}
__device__ __forceinline__ float rcp_fast(float x){
#if __has_builtin(__builtin_amdgcn_rcpf)
    return __builtin_amdgcn_rcpf(x);           // v_rcp_f32
#else
    return __fdividef(1.0f, x);
#endif
}
// sigma(x) with pre-scaled argument t = log2e * x
__device__ __forceinline__ float sigm2(float t){
    return rcp_fast(1.0f + exp2_fast(-t));
}
// tanh(y) with pre-scaled argument t = 2*log2e * y
__device__ __forceinline__ float tanh2(float t){
    return fmaf(-2.0f, rcp_fast(exp2_fast(t) + 1.0f), 1.0f);
}
__device__ __forceinline__ f32x4 mfma16(bf16x8 a, bf16x8 b, f32x4 c){
    return __builtin_amdgcn_mfma_f32_16x16x32_bf16(a, b, c, 0, 0, 0);
}
// packed f32x2 -> bf16x2 (RNE) in one instruction
__device__ __forceinline__ unsigned int cvtpk(float lo, float hi){
    unsigned int r;
    asm("v_cvt_pk_bf16_f32 %0, %1, %2" : "=v"(r) : "v"(lo), "v"(hi));
    return r;
}
// A-fragment: 8 contiguous k's of W[n][k], pre-scaled then bf16-rounded.
__device__ __forceinline__ bf16x8 mk_frag(const void* W, int n, int kb, bool f32, float sc){
    us8 tmp;
    #pragma unroll
    for (int j = 0; j < 8; ++j){
        float v = f32 ? ((const float*)W)[n * 64 + kb + j]
                      : bf2f(((const ushort_t*)W)[n * 64 + kb + j]);
        tmp[j] = f2bf(v * sc);
    }
    return __builtin_bit_cast(bf16x8, tmp);
}

// ---- L0 step: hA(t) = GRU0(x(t), hA(t-1)), all state in registers. ----
// EIN/EOUT: ui2[4] quarters (alternating buffers). Publishes to ring.
#define L0_STEP(EIN, EOUT, T) do {                                          \
    ui4 u0_ = {EIN[0][0], EIN[0][1], EIN[1][0], EIN[1][1]};                 \
    ui4 u1_ = {EIN[2][0], EIN[2][1], EIN[3][0], EIN[3][1]};                 \
    bf16x8 B0_ = __builtin_bit_cast(bf16x8, u0_);                           \
    bf16x8 B1_ = __builtin_bit_cast(bf16x8, u1_);                           \
    float xb_ = xbuf[b * XPAD + (T)];                                       \
    unsigned int bxw_ = (hp == 0) ? cvtpk(xb_, 1.0f) : 0u;                  \
    ui4 bxu_ = {bxw_, 0u, 0u, 0u};                                          \
    bf16x8 BX_ = __builtin_bit_cast(bf16x8, bxu_);                          \
    _Pragma("unroll")                                                       \
    for (int tau = 0; tau < 4; ++tau){                                      \
        f32x4 z4_ = {0.f, 0.f, 0.f, 0.f};                                   \
        f32x4 aR_ = mfma16(wx[0][tau], BX_, z4_);                           \
        f32x4 aZ_ = mfma16(wx[1][tau], BX_, z4_);                           \
        f32x4 aX_ = mfma16(wx[2][tau], BX_, z4_);                           \
        aR_ = mfma16(wh[0][tau][0], B0_, aR_);                              \
        aR_ = mfma16(wh[0][tau][1], B1_, aR_);                              \
        aZ_ = mfma16(wh[1][tau][0], B0_, aZ_);                              \
        aZ_ = mfma16(wh[1][tau][1], B1_, aZ_);                              \
        f32x4 aN_ = mfma16(wh[2][tau][0], B0_, cbNh[tau]);                  \
        aN_ = mfma16(wh[2][tau][1], B1_, aN_);                              \
        _Pragma("unroll")                                                   \
        for (int r_ = 0; r_ < 4; ++r_){                                     \
            float rg_ = sigm2(aR_[r_]);                                     \
            float zg_ = sigm2(aZ_[r_]);                                     \
            float ng_ = tanh2(aX_[r_] + rg_ * aN_[r_]);                     \
            hS[tau][r_] = ng_ + zg_ * (hS[tau][r_] - ng_);                  \
        }                                                                   \
        EOUT[tau][0] = cvtpk(hS[tau][0], hS[tau][1]);                       \
        EOUT[tau][1] = cvtpk(hS[tau][2], hS[tau][3]);                       \
        ring[(T) & (RING - 1)][tau][l] = EOUT[tau];                         \
    }                                                                       \
} while (0)

// ---- L1 step: hB(t) = GRU1(hA(t) [ring], hB(t-1) [regs]). ----
#define LD_STASH(G, TAU, F) \
    __builtin_bit_cast(bf16x8, stash[((G) * 4 + (TAU)) * 2 + (F)][l])
#define L1_STEP(EIN, EOUT, T) do {                                          \
    const int sl_ = (T) & (RING - 1);                                       \
    ui2 q0_ = ring[sl_][0][l], q1_ = ring[sl_][1][l];                       \
    ui2 q2_ = ring[sl_][2][l], q3_ = ring[sl_][3][l];                       \
    ui4 ga0_ = {q0_[0], q0_[1], q1_[0], q1_[1]};                            \
    ui4 ga1_ = {q2_[0], q2_[1], q3_[0], q3_[1]};                            \
    bf16x8 gA0_ = __builtin_bit_cast(bf16x8, ga0_);                         \
    bf16x8 gA1_ = __builtin_bit_cast(bf16x8, ga1_);                         \
    ui4 u0_ = {EIN[0][0], EIN[0][1], EIN[1][0], EIN[1][1]};                 \
    ui4 u1_ = {EIN[2][0], EIN[2][1], EIN[3][0], EIN[3][1]};                 \
    bf16x8 B0_ = __builtin_bit_cast(bf16x8, u0_);                           \
    bf16x8 B1_ = __builtin_bit_cast(bf16x8, u1_);                           \
    _Pragma("unroll")                                                       \
    for (int tau = 0; tau < 4; ++tau){                                      \
        f32x4 aR_ = mfma16(LD_STASH(0, tau, 0), gA0_, cbR[tau]);            \
        aR_ = mfma16(LD_STASH(0, tau, 1), gA1_, aR_);                       \
        aR_ = mfma16(wh[0][tau][0], B0_, aR_);                              \
        aR_ = mfma16(wh[0][tau][1], B1_, aR_);                              \
        f32x4 aZ_ = mfma16(LD_STASH(1, tau, 0), gA0_, cbZ[tau]);            \
        aZ_ = mfma16(LD_STASH(1, tau, 1), gA1_, aZ_);                       \
        aZ_ = mfma16(wh[1][tau][0], B0_, aZ_);                              \
        aZ_ = mfma16(wh[1][tau][1], B1_, aZ_);                              \
        f32x4 aX_ = mfma16(LD_STASH(2, tau, 0), gA0_, cbNx[tau]);           \
        aX_ = mfma16(LD_STASH(2, tau, 1), gA1_, aX_);                       \
        f32x4 aN_ = mfma16(wh[2][tau][0], B0_, cbNh[tau]);                  \
        aN_ = mfma16(wh[2][tau][1], B1_, aN_);                              \
        _Pragma("unroll")                                                   \
        for (int r_ = 0; r_ < 4; ++r_){                                     \
            float rg_ = sigm2(aR_[r_]);                                     \
            float zg_ = sigm2(aZ_[r_]);                                     \
            float ng_ = tanh2(aX_[r_] + rg_ * aN_[r_]);                     \
            hS[tau][r_] = ng_ + zg_ * (hS[tau][r_] - ng_);                  \
        }                                                                   \
        EOUT[tau][0] = cvtpk(hS[tau][0], hS[tau][1]);                       \
        EOUT[tau][1] = cvtpk(hS[tau][2], hS[tau][3]);                       \
    }                                                                       \
} while (0)

__global__ __launch_bounds__(128, 1) void gru_fused(
    const void* __restrict__ xv,
    const void* __restrict__ Wih0, const void* __restrict__ Whh0,
    const void* __restrict__ bih0, const void* __restrict__ bhh0,
    const void* __restrict__ Wih1, const void* __restrict__ Whh1,
    const void* __restrict__ bih1, const void* __restrict__ bhh1,
    const void* __restrict__ Wfc,  const void* __restrict__ bfc,
    void* __restrict__ outv)
{
    __shared__ float xbuf[16 * XPAD];      // staged x, f32        (32.8 KB)
    __shared__ ui2   ring[RING][4][64];    // hA handoff ring      (32 KB)
    __shared__ ui4   stash[24][64];        // Wih1 frags (L1 priv) (24.5 KB)

    const int tid = threadIdx.x;
    const int wv  = tid >> 6;              // 0 = L0 wave, 1 = L1 wave
    const int l   = tid & 63;
    const int b   = l & 15;                // batch row (MFMA D column)
    const int hp  = l >> 4;                // k-group (MFMA D row block)
    const int am  = l & 15;                // A-operand row this lane loads
    const long row0 = (long)blockIdx.x * 16;

    // dtype detection (uniform): fp32 misread as bf16 -> mantissa-noise
    // exponents in even ushort slots; true bf16 never exceeds exp 150.
    bool f32 = false;
    {
        const ushort_t* xs = (const ushort_t*)xv;
        for (int j = 0; j < 64; ++j){
            int e = (xs[2 * j] >> 7) & 0xFF;
            if (e > 150) f32 = true;
        }
    }

    // stage x: 16 rows x 512, both waves cooperate, convert to f32
    if (f32){
        for (int idx = tid; idx < 16 * (T_LEN / 4); idx += 128){
            const int r = idx >> 7, sg = idx & 127;
            f32x4 v = ((const f32x4*)((const float*)xv + (row0 + r) * T_LEN))[sg];
            #pragma unroll
            for (int j = 0; j < 4; ++j) xbuf[r * XPAD + sg * 4 + j] = v[j];
        }
    } else {
        for (int idx = tid; idx < 16 * (T_LEN / 8); idx += 128){
            const int r = idx >> 6, sg = idx & 63;
            us8 v = ((const us8*)((const ushort_t*)xv + (row0 + r) * T_LEN))[sg];
            #pragma unroll
            for (int j = 0; j < 8; ++j) xbuf[r * XPAD + sg * 8 + j] = bf2f(v[j]);
        }
    }

    const float gsc0 = LOG2E, gsc2 = 2.0f * LOG2E;

    __syncthreads();                       // B0: xbuf staged

    if (wv == 0){
        // ======================= LAYER-0 WAVE =======================
        bf16x8 wh[3][4][2];                // Whh0, permuted, resident
        bf16x8 wx[3][4];                   // x-weight+bias frag (k0=x, k1=1)
        f32x4  cbNh[4];                    // bhh-n as C-in (f32 precision)
        #pragma unroll
        for (int g = 0; g < 3; ++g){
            const float sc = (g == 2) ? gsc2 : gsc0;
            #pragma unroll
            for (int tau = 0; tau < 4; ++tau){
                const int grow = g * 64 + 32 * (tau >> 1) + 8 * (am >> 2)
                               + 4 * (tau & 1) + (am & 3);
                wh[g][tau][0] = mk_frag(Whh0, grow, 8 * hp,      f32, sc);
                wh[g][tau][1] = mk_frag(Whh0, grow, 32 + 8 * hp, f32, sc);
                us8 t8 = {0, 0, 0, 0, 0, 0, 0, 0};
                if (hp == 0){
                    float wv_ = ld_any(Wih0, grow, f32) * sc;
                    float bv  = ld_any(bih0, grow, f32);
                    if (g < 2) bv += ld_any(bhh0, grow, f32);
                    bv *= sc;
                    t8[0] = f2bf(wv_);
                    t8[1] = f2bf(bv);
                }
                wx[g][tau] = __builtin_bit_cast(bf16x8, t8);
            }
        }
        #pragma unroll
        for (int tau = 0; tau < 4; ++tau){
            #pragma unroll
            for (int r = 0; r < 4; ++r){
                const int hc = 32 * (tau >> 1) + 8 * hp + 4 * (tau & 1) + r;
                cbNh[tau][r] = ld_any(bhh0, 128 + hc, f32) * gsc2;
            }
        }

        f32x4 hS[4] = {{0,0,0,0},{0,0,0,0},{0,0,0,0},{0,0,0,0}};
        ui2 eA[4] = {{0,0},{0,0},{0,0},{0,0}};
        ui2 eB[4];

        for (int k = 0; k < NI; ++k){
            const int t0 = k * KS;
            for (int s = 0; s < KS; s += 2){
                L0_STEP(eA, eB, t0 + s);
                L0_STEP(eB, eA, t0 + s + 1);
            }
            __syncthreads();               // chunk k published
        }
        __syncthreads();                   // pair with L1's last chunk
    } else {
        // ======================= LAYER-1 WAVE =======================
        // stash Wih1 frags in LDS (streamed per step; wave-private)
        #pragma unroll
        for (int g = 0; g < 3; ++g){
            const float sc = (g == 2) ? gsc2 : gsc0;
            #pragma unroll
            for (int tau = 0; tau < 4; ++tau){
                const int grow = g * 64 + 32 * (tau >> 1) + 8 * (am >> 2)
                               + 4 * (tau & 1) + (am & 3);
                stash[(g * 4 + tau) * 2 + 0][l] =
                    __builtin_bit_cast(ui4, mk_frag(Wih1, grow, 8 * hp,      f32, sc));
                stash[(g * 4 + tau) * 2 + 1][l] =
                    __builtin_bit_cast(ui4, mk_frag(Wih1, grow, 32 + 8 * hp, f32, sc));
            }
        }
        bf16x8 wh[3][4][2];                // Whh1, permuted, resident
        #pragma unroll
        for (int g = 0; g < 3; ++g){
            const float sc = (g == 2) ? gsc2 : gsc0;
            #pragma unroll
            for (int tau = 0; tau < 4; ++tau){
                const int grow = g * 64 + 32 * (tau >> 1) + 8 * (am >> 2)
                               + 4 * (tau & 1) + (am & 3);
                wh[g][tau][0] = mk_frag(Whh1, grow, 8 * hp,      f32, sc);
                wh[g][tau][1] = mk_frag(Whh1, grow, 32 + 8 * hp, f32, sc);
            }
        }
        f32x4 cbR[4], cbZ[4], cbNx[4], cbNh[4];
        #pragma unroll
        for (int tau = 0; tau < 4; ++tau){
            #pragma unroll
            for (int r = 0; r < 4; ++r){
                const int hc = 32 * (tau >> 1) + 8 * hp + 4 * (tau & 1) + r;
                cbR[tau][r]  = (ld_any(bih1, hc, f32)      + ld_any(bhh1, hc, f32))      * gsc0;
                cbZ[tau][r]  = (ld_any(bih1, 64 + hc, f32) + ld_any(bhh1, 64 + hc, f32)) * gsc0;
                cbNx[tau][r] = ld_any(bih1, 128 + hc, f32) * gsc2;
                cbNh[tau][r] = ld_any(bhh1, 128 + hc, f32) * gsc2;
            }
        }

        f32x4 hS[4] = {{0,0,0,0},{0,0,0,0},{0,0,0,0},{0,0,0,0}};
        ui2 eA[4] = {{0,0},{0,0},{0,0},{0,0}};
        ui2 eB[4];

        __syncthreads();                   // interval 0: idle (L0 fills chunk 0)
        for (int k = 1; k <= NI; ++k){
            const int t0 = (k - 1) * KS;
            for (int s = 0; s < KS; s += 2){
                L1_STEP(eA, eB, t0 + s);
                L1_STEP(eB, eA, t0 + s + 1);
            }
            __syncthreads();               // done with chunk k-1 ring half
        }

        // FC epilogue: hS = hB(511); lane holds 16 h-cols for batch b.
        float part = 0.0f;
        #pragma unroll
        for (int tau = 0; tau < 4; ++tau){
            #pragma unroll
            for (int r = 0; r < 4; ++r){
                const int hc = 32 * (tau >> 1) + 8 * hp + 4 * (tau & 1) + r;
                part = fmaf(ld_any(Wfc, hc, f32), hS[tau][r], part);
            }
        }
        part += __shfl_xor(part, 16);      // reduce across hp
        part += __shfl_xor(part, 32);
        if (l < 16){
            float s = part + ld_any(bfc, 0, f32);
            if (f32) ((float*)outv)[row0 + b] = s;
            else     ((ushort_t*)outv)[row0 + b] = f2bf(s);
        }
    }
}

extern "C" void kernel_launch(void* const* d_in, const int* in_sizes, int n_in,
                              void* d_out, int out_size, void* d_ws, size_t ws_size,
                              hipStream_t stream)
{
    (void)in_sizes; (void)n_in; (void)d_ws; (void)ws_size;
    const int B = out_size;               // O = 1 -> out_size == batch
    const int nblk = B / 16;              // 2048/16 = 128 blocks, 2 waves each
    gru_fused<<<nblk, 128, 0, stream>>>(
        d_in[0],
        d_in[1], d_in[2], d_in[3], d_in[4],
        d_in[5], d_in[6], d_in[7], d_in[8],
        d_in[9], d_in[10],
        d_out);
}

// Round 10
// 563.849 us; speedup vs baseline: 1.0433x; 1.0433x over previous
//
#include <hip/hip_runtime.h>

// UniversalGRU: 2-layer GRU (B=2048, T=512, D=1, H=64) + FC(64->1).
// R17: CHUNK-PIPELINED PRODUCER/CONSUMER. Session law (R8-R16):
// wall = 512 x per-step interval of the critical SERIAL wave; blocks/CUs
// are irrelevant (all parallel). R16 showed the serial wave's interval is
// dominated by (a) trans-pipe: 16 h-cols x 3 gates x 2 trans = 96 trans
// ops/step (~8cyc each wave64) and (b) any LDS reads inside the chain.
// R17 strips the serial waves to the irreducible recurrence only:
//  - wave 0 (L0): register hA recurrence (R16-proven), x-term via BX MFMA
//    (bf16 x from LDS), publishes hA quarters to an 8-slot ring.
//  - waves 1,2 (P0,P1): feed-forward X = Wih1*hA + biases for a whole
//    KS=4-step chunk from the ring (12 MFMA + 6 ds_write_b128 per step
//    each; no serial chain, trans-idle) -> f32 X buffer (double-buffered).
//  - wave 3 (C): hB recurrence: per step 12 ds_read_b128 (X, all known at
//    chunk start -> prefetchable), 24 MFMA (2-dep chains), 48 acts,
//    register hB. FC epilogue.
// Barrier every KS=4 steps (130 total vs R12's 513). Pipeline: interval i:
// L0 does chunk i, P does chunk i-1, C does chunk i-2. Ring/X lifetimes
// verified: writer and reader of each buffer parity are 2 intervals apart.
// 128 blocks x 256 threads, LDS ~131KB (1 block/CU; 90KB proven in R16).

#define T_LEN 512
#define KS    4
#define NC    (T_LEN / KS)      // 128 chunks
#define XP2   520
#define LOG2E 1.44269504088896f

typedef float          f32x4 __attribute__((ext_vector_type(4)));
typedef __bf16         bf16x8 __attribute__((ext_vector_type(8)));
typedef unsigned short us8   __attribute__((ext_vector_type(8)));
typedef unsigned int   ui4   __attribute__((ext_vector_type(4)));
typedef unsigned int   ui2   __attribute__((ext_vector_type(2)));
typedef unsigned short ushort_t;

__device__ __forceinline__ float bf2f(ushort_t b){
    unsigned int u = ((unsigned int)b) << 16;
    return __uint_as_float(u);
}
__device__ __forceinline__ ushort_t f2bf(float f){
    unsigned int u = __float_as_uint(f);
    u = (u + 0x7FFFu + ((u >> 16) & 1u)) >> 16;   // RNE
    return (ushort_t)u;
}
__device__ __forceinline__ float ld_any(const void* p, int i, bool f32){
    return f32 ? ((const float*)p)[i] : bf2f(((const ushort_t*)p)[i]);
}
__device__ __forceinline__ float exp2_fast(float x){
#if __has_builtin(__builtin_amdgcn_exp2f)
    return __builtin_amdgcn_exp2f(x);          // v_exp_f32 (2^x)
#else
    return __expf(0.6931471805599453f * x);
#endif
}
__device__ __forceinline__ float rcp_fast(float x){
#if __has_builtin(__builtin_amdgcn_rcpf)
    return __builtin_amdgcn_rcpf(x);           // v_rcp_f32
#else
    return __fdividef(1.0f, x);
#endif
}
// sigma(x) with pre-scaled argument t = log2e * x
__device__ __forceinline__ float sigm2(float t){
    return rcp_fast(1.0f + exp2_fast(-t));
}
// tanh(y) with pre-scaled argument t = 2*log2e * y
__device__ __forceinline__ float tanh2(float t){
    return fmaf(-2.0f, rcp_fast(exp2_fast(t) + 1.0f), 1.0f);
}
__device__ __forceinline__ f32x4 mfma16(bf16x8 a, bf16x8 b, f32x4 c){
    return __builtin_amdgcn_mfma_f32_16x16x32_bf16(a, b, c, 0, 0, 0);
}
// packed f32x2 -> bf16x2 (RNE) in one instruction
__device__ __forceinline__ unsigned int cvtpk(float lo, float hi){
    unsigned int r;
    asm("v_cvt_pk_bf16_f32 %0, %1, %2" : "=v"(r) : "v"(lo), "v"(hi));
    return r;
}
// A-fragment: 8 contiguous k's of W[n][k], pre-scaled then bf16-rounded.
__device__ __forceinline__ bf16x8 mk_frag(const void* W, int n, int kb, bool f32, float sc){
    us8 tmp;
    #pragma unroll
    for (int j = 0; j < 8; ++j){
        float v = f32 ? ((const float*)W)[n * 64 + kb + j]
                      : bf2f(((const ushort_t*)W)[n * 64 + kb + j]);
        tmp[j] = f2bf(v * sc);
    }
    return __builtin_bit_cast(bf16x8, tmp);
}

// ---- L0 step: hA(t) = GRU0(x(t), hA(t-1)), all state in registers. ----
#define L0_STEP(EIN, EOUT, T) do {                                          \
    ui4 u0_ = {EIN[0][0], EIN[0][1], EIN[1][0], EIN[1][1]};                 \
    ui4 u1_ = {EIN[2][0], EIN[2][1], EIN[3][0], EIN[3][1]};                 \
    bf16x8 B0_ = __builtin_bit_cast(bf16x8, u0_);                           \
    bf16x8 B1_ = __builtin_bit_cast(bf16x8, u1_);                           \
    float xb_ = bf2f(xb16[b][T]);                                           \
    unsigned int bxw_ = (hp == 0) ? cvtpk(xb_, 1.0f) : 0u;                  \
    ui4 bxu_ = {bxw_, 0u, 0u, 0u};                                          \
    bf16x8 BX_ = __builtin_bit_cast(bf16x8, bxu_);                          \
    _Pragma("unroll")                                                       \
    for (int tau = 0; tau < 4; ++tau){                                      \
        f32x4 z4_ = {0.f, 0.f, 0.f, 0.f};                                   \
        f32x4 aR_ = mfma16(wx[0][tau], BX_, z4_);                           \
        f32x4 aZ_ = mfma16(wx[1][tau], BX_, z4_);                           \
        f32x4 aX_ = mfma16(wx[2][tau], BX_, z4_);                           \
        aR_ = mfma16(wh[0][tau][0], B0_, aR_);                              \
        aR_ = mfma16(wh[0][tau][1], B1_, aR_);                              \
        aZ_ = mfma16(wh[1][tau][0], B0_, aZ_);                              \
        aZ_ = mfma16(wh[1][tau][1], B1_, aZ_);                              \
        f32x4 aN_ = mfma16(wh[2][tau][0], B0_, cbNh[tau]);                  \
        aN_ = mfma16(wh[2][tau][1], B1_, aN_);                              \
        _Pragma("unroll")                                                   \
        for (int r_ = 0; r_ < 4; ++r_){                                     \
            float rg_ = sigm2(aR_[r_]);                                     \
            float zg_ = sigm2(aZ_[r_]);                                     \
            float ng_ = tanh2(aX_[r_] + rg_ * aN_[r_]);                     \
            hS[tau][r_] = ng_ + zg_ * (hS[tau][r_] - ng_);                  \
        }                                                                   \
        EOUT[tau][0] = cvtpk(hS[tau][0], hS[tau][1]);                       \
        EOUT[tau][1] = cvtpk(hS[tau][2], hS[tau][3]);                       \
        ring[(T) & 7][tau][l] = EOUT[tau];                                  \
    }                                                                       \
} while (0)

// ---- C step: hB(t) = GRU1 from precomputed X (LDS) + Whh1*hB (regs). ----
#define C_STEP(EIN, EOUT, XB, S) do {                                       \
    ui4 u0_ = {EIN[0][0], EIN[0][1], EIN[1][0], EIN[1][1]};                 \
    ui4 u1_ = {EIN[2][0], EIN[2][1], EIN[3][0], EIN[3][1]};                 \
    bf16x8 B0_ = __builtin_bit_cast(bf16x8, u0_);                           \
    bf16x8 B1_ = __builtin_bit_cast(bf16x8, u1_);                           \
    _Pragma("unroll")                                                       \
    for (int tau = 0; tau < 4; ++tau){                                      \
        f32x4 aR_ = Xbuf[XB][S][0][tau][l];                                 \
        aR_ = mfma16(wh[0][tau][0], B0_, aR_);                              \
        aR_ = mfma16(wh[0][tau][1], B1_, aR_);                              \
        f32x4 aZ_ = Xbuf[XB][S][1][tau][l];                                 \
        aZ_ = mfma16(wh[1][tau][0], B0_, aZ_);                              \
        aZ_ = mfma16(wh[1][tau][1], B1_, aZ_);                              \
        f32x4 aX_ = Xbuf[XB][S][2][tau][l];                                 \
        f32x4 aN_ = mfma16(wh[2][tau][0], B0_, cbNh[tau]);                  \
        aN_ = mfma16(wh[2][tau][1], B1_, aN_);                              \
        _Pragma("unroll")                                                   \
        for (int r_ = 0; r_ < 4; ++r_){                                     \
            float rg_ = sigm2(aR_[r_]);                                     \
            float zg_ = sigm2(aZ_[r_]);                                     \
            float ng_ = tanh2(aX_[r_] + rg_ * aN_[r_]);                     \
            hS[tau][r_] = ng_ + zg_ * (hS[tau][r_] - ng_);                  \
        }                                                                   \
        EOUT[tau][0] = cvtpk(hS[tau][0], hS[tau][1]);                       \
        EOUT[tau][1] = cvtpk(hS[tau][2], hS[tau][3]);                       \
    }                                                                       \
} while (0)

__global__ __launch_bounds__(256, 1) void gru_fused(
    const void* __restrict__ xv,
    const void* __restrict__ Wih0, const void* __restrict__ Whh0,
    const void* __restrict__ bih0, const void* __restrict__ bhh0,
    const void* __restrict__ Wih1, const void* __restrict__ Whh1,
    const void* __restrict__ bih1, const void* __restrict__ bhh1,
    const void* __restrict__ Wfc,  const void* __restrict__ bfc,
    void* __restrict__ outv)
{
    __shared__ ushort_t xb16[16][XP2];          // x as bf16      (16.6 KB)
    __shared__ ui2   ring[8][4][64];            // hA handoff     (16 KB)
    __shared__ f32x4 Xbuf[2][KS][3][4][64];     // Wih1*hA+bias   (98.3 KB)

    const int tid = threadIdx.x;
    const int wv  = tid >> 6;              // 0=L0, 1=P0, 2=P1, 3=C
    const int l   = tid & 63;
    const int b   = l & 15;                // batch row (MFMA D column)
    const int hp  = l >> 4;                // k-group (MFMA D row block)
    const int am  = l & 15;                // A-operand row this lane loads
    const long row0 = (long)blockIdx.x * 16;

    // dtype detection (uniform): fp32 misread as bf16 -> mantissa-noise
    // exponents in even ushort slots; true bf16 never exceeds exp 150.
    bool f32 = false;
    {
        const ushort_t* xs = (const ushort_t*)xv;
        for (int j = 0; j < 64; ++j){
            int e = (xs[2 * j] >> 7) & 0xFF;
            if (e > 150) f32 = true;
        }
    }

    // stage x (16 rows x 512) as bf16, all 4 waves cooperate
    if (f32){
        for (int idx = tid; idx < 16 * (T_LEN / 4); idx += 256){
            const int r = idx >> 7, sg = idx & 127;
            f32x4 v = ((const f32x4*)((const float*)xv + (row0 + r) * T_LEN))[sg];
            #pragma unroll
            for (int j = 0; j < 4; ++j) xb16[r][sg * 4 + j] = f2bf(v[j]);
        }
    } else {
        for (int idx = tid; idx < 16 * (T_LEN / 8); idx += 256){
            const int r = idx >> 6, sg = idx & 63;
            us8 v = ((const us8*)((const ushort_t*)xv + (row0 + r) * T_LEN))[sg];
            #pragma unroll
            for (int j = 0; j < 8; ++j) xb16[r][sg * 8 + j] = v[j];
        }
    }

    const float gsc0 = LOG2E, gsc2 = 2.0f * LOG2E;

    __syncthreads();                       // staging complete

    if (wv == 0){
        // ======================= L0: hA recurrence =======================
        bf16x8 wh[3][4][2];                // Whh0, permuted, resident
        bf16x8 wx[3][4];                   // x-weight+bias frag (k0=x, k1=1)
        f32x4  cbNh[4];                    // bhh0-n as C-in
        #pragma unroll
        for (int g = 0; g < 3; ++g){
            const float sc = (g == 2) ? gsc2 : gsc0;
            #pragma unroll
            for (int tau = 0; tau < 4; ++tau){
                const int grow = g * 64 + 32 * (tau >> 1) + 8 * (am >> 2)
                               + 4 * (tau & 1) + (am & 3);
                wh[g][tau][0] = mk_frag(Whh0, grow, 8 * hp,      f32, sc);
                wh[g][tau][1] = mk_frag(Whh0, grow, 32 + 8 * hp, f32, sc);
                us8 t8 = {0, 0, 0, 0, 0, 0, 0, 0};
                if (hp == 0){
                    float wv_ = ld_any(Wih0, grow, f32) * sc;
                    float bv  = ld_any(bih0, grow, f32);
                    if (g < 2) bv += ld_any(bhh0, grow, f32);
                    bv *= sc;
                    t8[0] = f2bf(wv_);
                    t8[1] = f2bf(bv);
                }
                wx[g][tau] = __builtin_bit_cast(bf16x8, t8);
            }
        }
        #pragma unroll
        for (int tau = 0; tau < 4; ++tau){
            #pragma unroll
            for (int r = 0; r < 4; ++r){
                const int hc = 32 * (tau >> 1) + 8 * hp + 4 * (tau & 1) + r;
                cbNh[tau][r] = ld_any(bhh0, 128 + hc, f32) * gsc2;
            }
        }
        f32x4 hS[4] = {{0,0,0,0},{0,0,0,0},{0,0,0,0},{0,0,0,0}};
        ui2 eA[4] = {{0,0},{0,0},{0,0},{0,0}};
        ui2 eB[4];

        for (int i = 0; i <= NC + 1; ++i){
            if (i < NC){
                const int t0 = i * KS;
                #pragma unroll
                for (int s = 0; s < KS; s += 2){
                    L0_STEP(eA, eB, t0 + s);
                    L0_STEP(eB, eA, t0 + s + 1);
                }
            }
            __syncthreads();
        }
    } else if (wv <= 2){
        // ============ P0/P1: X = Wih1*hA + biases (feed-forward) ============
        const int tbase = (wv - 1) * 2;    // global tau = tbase + lt
        bf16x8 wi[3][2][2];                // Wih1 frags for 2 tau
        f32x4  cbR[2], cbZ[2], cbNx[2];
        #pragma unroll
        for (int g = 0; g < 3; ++g){
            const float sc = (g == 2) ? gsc2 : gsc0;
            #pragma unroll
            for (int lt = 0; lt < 2; ++lt){
                const int gt = tbase + lt;
                const int grow = g * 64 + 32 * (gt >> 1) + 8 * (am >> 2)
                               + 4 * (gt & 1) + (am & 3);
                wi[g][lt][0] = mk_frag(Wih1, grow, 8 * hp,      f32, sc);
                wi[g][lt][1] = mk_frag(Wih1, grow, 32 + 8 * hp, f32, sc);
            }
        }
        #pragma unroll
        for (int lt = 0; lt < 2; ++lt){
            const int gt = tbase + lt;
            #pragma unroll
            for (int r = 0; r < 4; ++r){
                const int hc = 32 * (gt >> 1) + 8 * hp + 4 * (gt & 1) + r;
                cbR[lt][r]  = (ld_any(bih1, hc, f32)      + ld_any(bhh1, hc, f32))      * gsc0;
                cbZ[lt][r]  = (ld_any(bih1, 64 + hc, f32) + ld_any(bhh1, 64 + hc, f32)) * gsc0;
                cbNx[lt][r] = ld_any(bih1, 128 + hc, f32) * gsc2;
            }
        }

        for (int i = 0; i <= NC + 1; ++i){
            if (i >= 1 && i <= NC){
                const int c = i - 1, t0 = c * KS, xb = c & 1;
                #pragma unroll
                for (int s = 0; s < KS; ++s){
                    const int slot = (t0 + s) & 7;
                    ui2 q0 = ring[slot][0][l], q1 = ring[slot][1][l];
                    ui2 q2 = ring[slot][2][l], q3 = ring[slot][3][l];
                    ui4 ga0 = {q0[0], q0[1], q1[0], q1[1]};
                    ui4 ga1 = {q2[0], q2[1], q3[0], q3[1]};
                    bf16x8 gA0 = __builtin_bit_cast(bf16x8, ga0);
                    bf16x8 gA1 = __builtin_bit_cast(bf16x8, ga1);
                    #pragma unroll
                    for (int lt = 0; lt < 2; ++lt){
                        const int gt = tbase + lt;
                        f32x4 aR = mfma16(wi[0][lt][0], gA0, cbR[lt]);
                        aR = mfma16(wi[0][lt][1], gA1, aR);
                        Xbuf[xb][s][0][gt][l] = aR;
                        f32x4 aZ = mfma16(wi[1][lt][0], gA0, cbZ[lt]);
                        aZ = mfma16(wi[1][lt][1], gA1, aZ);
                        Xbuf[xb][s][1][gt][l] = aZ;
                        f32x4 aX = mfma16(wi[2][lt][0], gA0, cbNx[lt]);
                        aX = mfma16(wi[2][lt][1], gA1, aX);
                        Xbuf[xb][s][2][gt][l] = aX;
                    }
                }
            }
            __syncthreads();
        }
    } else {
        // ======================= C: hB recurrence =======================
        bf16x8 wh[3][4][2];                // Whh1, permuted, resident
        f32x4  cbNh[4];                    // bhh1-n as C-in
        #pragma unroll
        for (int g = 0; g < 3; ++g){
            const float sc = (g == 2) ? gsc2 : gsc0;
            #pragma unroll
            for (int tau = 0; tau < 4; ++tau){
                const int grow = g * 64 + 32 * (tau >> 1) + 8 * (am >> 2)
                               + 4 * (tau & 1) + (am & 3);
                wh[g][tau][0] = mk_frag(Whh1, grow, 8 * hp,      f32, sc);
                wh[g][tau][1] = mk_frag(Whh1, grow, 32 + 8 * hp, f32, sc);
            }
        }
        #pragma unroll
        for (int tau = 0; tau < 4; ++tau){
            #pragma unroll
            for (int r = 0; r < 4; ++r){
                const int hc = 32 * (tau >> 1) + 8 * hp + 4 * (tau & 1) + r;
                cbNh[tau][r] = ld_any(bhh1, 128 + hc, f32) * gsc2;
            }
        }
        f32x4 hS[4] = {{0,0,0,0},{0,0,0,0},{0,0,0,0},{0,0,0,0}};
        ui2 eA[4] = {{0,0},{0,0},{0,0},{0,0}};
        ui2 eB[4];

        for (int i = 0; i <= NC + 1; ++i){
            if (i >= 2){
                const int c = i - 2, xb = c & 1;
                #pragma unroll
                for (int s = 0; s < KS; s += 2){
                    C_STEP(eA, eB, xb, s);
                    C_STEP(eB, eA, xb, s + 1);
                }
            }
            __syncthreads();
        }

        // FC epilogue: hS = hB(511); lane holds 16 h-cols for batch b.
        float part = 0.0f;
        #pragma unroll
        for (int tau = 0; tau < 4; ++tau){
            #pragma unroll
            for (int r = 0; r < 4; ++r){
                const int hc = 32 * (tau >> 1) + 8 * hp + 4 * (tau & 1) + r;
                part = fmaf(ld_any(Wfc, hc, f32), hS[tau][r], part);
            }
        }
        part += __shfl_xor(part, 16);      // reduce across hp
        part += __shfl_xor(part, 32);
        if (l < 16){
            float s = part + ld_any(bfc, 0, f32);
            if (f32) ((float*)outv)[row0 + b] = s;
            else     ((ushort_t*)outv)[row0 + b] = f2bf(s);
        }
    }
}

extern "C" void kernel_launch(void* const* d_in, const int* in_sizes, int n_in,
                              void* d_out, int out_size, void* d_ws, size_t ws_size,
                              hipStream_t stream)
{
    (void)in_sizes; (void)n_in; (void)d_ws; (void)ws_size;
    const int B = out_size;               // O = 1 -> out_size == batch
    const int nblk = B / 16;              // 2048/16 = 128 blocks, 4 waves each
    gru_fused<<<nblk, 256, 0, stream>>>(
        d_in[0],
        d_in[1], d_in[2], d_in[3], d_in[4],
        d_in[5], d_in[6], d_in[7], d_in[8],
        d_in[9], d_in[10],
        d_out);
}

// Round 11
// 552.397 us; speedup vs baseline: 1.0649x; 1.0207x over previous
//
#include <hip/hip_runtime.h>

// UniversalGRU: 2-layer GRU (B=2048, T=512, D=1, H=64) + FC(64->1).
// R18 = R12 x 2 GROUPS IN SEPARATE WAVES. R12 (296us, best): 8 waves,
// tau-single split, 2 waves/SIMD, interval 1390 cyc = ~520 issue + ~870
// chain/barrier stall. R16/R17 (serial-wave designs) proved concentrating
// a layer in one wave serializes its 96 trans ops in one in-order stream;
// R15's in-wave G=2 failure traced to per-step GLOBAL x loads (barrier
// drains vmcnt(0) -> ~900 cyc exposed), not the G=2 concept.
// R18: 1024-thread blocks = TWO complete R12 structures (two independent
// 16-row groups) sharing one barrier, group-indexed LDS, x in LDS (no
// vmem in loop). 4 waves/SIMD: while group A's waves stall in their
// ds_read->MFMA->trans chains, group B's waves issue -- dynamic
// interleaving by the SIMD scheduler (robust, unlike compiler static
// scheduling of in-wave ILP). Per-wave work and barrier count (513)
// identical to R12. 64 blocks x 1024 threads, LDS ~82KB, VGPR ~70.

#define T_LEN 512
#define GPB   2
#define XPAD  513
#define LOG2E 1.44269504088896f

typedef float          f32x4 __attribute__((ext_vector_type(4)));
typedef __bf16         bf16x8 __attribute__((ext_vector_type(8)));
typedef unsigned short us8   __attribute__((ext_vector_type(8)));
typedef unsigned int   ui4   __attribute__((ext_vector_type(4)));
typedef unsigned int   ui2   __attribute__((ext_vector_type(2)));
typedef unsigned short ushort_t;

__device__ __forceinline__ float bf2f(ushort_t b){
    unsigned int u = ((unsigned int)b) << 16;
    return __uint_as_float(u);
}
__device__ __forceinline__ ushort_t f2bf(float f){
    unsigned int u = __float_as_uint(f);
    u = (u + 0x7FFFu + ((u >> 16) & 1u)) >> 16;   // RNE
    return (ushort_t)u;
}
__device__ __forceinline__ float ld_any(const void* p, int i, bool f32){
    return f32 ? ((const float*)p)[i] : bf2f(((const ushort_t*)p)[i]);
}
__device__ __forceinline__ float exp2_fast(float x){
#if __has_builtin(__builtin_amdgcn_exp2f)
    return __builtin_amdgcn_exp2f(x);          // v_exp_f32 (2^x)
#else
    return __expf(0.6931471805599453f * x);
#endif
}
__device__ __forceinline__ float rcp_fast(float x){
#if __has_builtin(__builtin_amdgcn_rcpf)
    return __builtin_amdgcn_rcpf(x);           // v_rcp_f32
#else
    return __fdividef(1.0f, x);
#endif
}
// sigma(x) with pre-scaled argument t = log2e * x
__device__ __forceinline__ float sigm2(float t){
    return rcp_fast(1.0f + exp2_fast(-t));
}
// tanh(y) with pre-scaled argument t = 2*log2e * y
__device__ __forceinline__ float tanh2(float t){
    return fmaf(-2.0f, rcp_fast(exp2_fast(t) + 1.0f), 1.0f);
}
__device__ __forceinline__ f32x4 mfma16(bf16x8 a, bf16x8 b, f32x4 c){
    return __builtin_amdgcn_mfma_f32_16x16x32_bf16(a, b, c, 0, 0, 0);
}
// packed f32x2 -> bf16x2 (RNE) in one instruction
__device__ __forceinline__ unsigned int cvtpk(float lo, float hi){
    unsigned int r;
    asm("v_cvt_pk_bf16_f32 %0, %1, %2" : "=v"(r) : "v"(lo), "v"(hi));
    return r;
}
// A-fragment: 8 contiguous k's of W[n][k], pre-scaled then bf16-rounded.
__device__ __forceinline__ bf16x8 mk_frag(const void* W, int n, int kb, bool f32, float sc){
    us8 tmp;
    #pragma unroll
    for (int j = 0; j < 8; ++j){
        float v = f32 ? ((const float*)W)[n * 64 + kb + j]
                      : bf2f(((const ushort_t*)W)[n * 64 + kb + j]);
        tmp[j] = f2bf(v * sc);
    }
    return __builtin_bit_cast(bf16x8, tmp);
}

__global__ __launch_bounds__(1024, 1) void gru_fused(
    const void* __restrict__ xv,
    const void* __restrict__ Wih0, const void* __restrict__ Whh0,
    const void* __restrict__ bih0, const void* __restrict__ bhh0,
    const void* __restrict__ Wih1, const void* __restrict__ Whh1,
    const void* __restrict__ bih1, const void* __restrict__ bhh1,
    const void* __restrict__ Wfc,  const void* __restrict__ bfc,
    void* __restrict__ outv)
{
    __shared__ float xbuf[GPB][16 * XPAD];   // staged x, f32       (65.7 KB)
    // h exchange: [group][parity][quarter tau][lane], ui2 = 4 bf16 frag layout
    __shared__ ui2   hAq[GPB][2][4][64];     // (8 KB)
    __shared__ ui2   hBq[GPB][2][4][64];     // (8 KB)
    __shared__ float fcb[GPB][4][16];        // FC cross-wave partials

    const int tid   = threadIdx.x;
    const int grp   = tid >> 9;            // group 0 / 1 (independent 16 rows)
    const int stid  = tid & 511;           // R12 thread id within group
    const int wv    = stid >> 6;           // 0..7
    const int layer = wv >> 2;             // 0 = GRU0 waves, 1 = GRU1 waves
    const int tau   = wv & 3;              // weight tile this wave owns
    const int l  = tid & 63;
    const int b  = l & 15;                 // batch row (MFMA D column)
    const int hp = l >> 4;                 // k-group (MFMA D row block)
    const int am = l & 15;                 // A-operand row this lane loads
    const long row0 = (long)blockIdx.x * (16 * GPB) + grp * 16;

    // dtype detection (uniform): fp32 misread as bf16 -> mantissa-noise
    // exponents in even ushort slots; true bf16 never exceeds exp 150.
    bool f32 = false;
    {
        const ushort_t* xs = (const ushort_t*)xv;
        for (int j = 0; j < 64; ++j){
            int e = (xs[2 * j] >> 7) & 0xFF;
            if (e > 150) f32 = true;
        }
    }

    // zero exchange buffers (h(-1) = 0, h(-2) = 0; both parities, both groups)
    {
        ui2 z = {0u, 0u};
        ui2* pa = &hAq[0][0][0][0];
        ui2* pb = &hBq[0][0][0][0];
        for (int k = tid; k < GPB * 2 * 4 * 64; k += 1024){ pa[k] = z; pb[k] = z; }
    }
    // stage x: each group's 512 threads stage its own 16 rows x 512, f32
    if (f32){
        for (int idx = stid; idx < 16 * (T_LEN / 4); idx += 512){
            const int r = idx >> 7, sg = idx & 127;
            f32x4 v = ((const f32x4*)((const float*)xv + (row0 + r) * T_LEN))[sg];
            #pragma unroll
            for (int j = 0; j < 4; ++j) xbuf[grp][r * XPAD + sg * 4 + j] = v[j];
        }
    } else {
        for (int idx = stid; idx < 16 * (T_LEN / 8); idx += 512){
            const int r = idx >> 6, sg = idx & 63;
            us8 v = ((const us8*)((const ushort_t*)xv + (row0 + r) * T_LEN))[sg];
            #pragma unroll
            for (int j = 0; j < 8; ++j) xbuf[grp][r * XPAD + sg * 8 + j] = bf2f(v[j]);
        }
    }

    const float gsc0 = LOG2E, gsc2 = 2.0f * LOG2E;

    // ---- weight / bias setup (per wave role; identical for both groups) ----
    // Permuted gate row for tile tau:
    //   grow(g) = g*64 + 32*(tau>>1) + 8*(am>>2) + 4*(tau&1) + (am&3)
    // Lane's D outputs land at h-col hc(r) = hb0 + r,
    //   hb0 = 32*(tau>>1) + 8*hp + 4*(tau&1)  -- the ui2 quarter published.
    bf16x8 wA[3][2];                       // L0: Whh0. L1: Wih1.
    bf16x8 wH[3][2];                       // L1 only: Whh1.
    f32x4 cbR, cbZ, cbNx, cbNh;
    f32x4 cwR, cwZ, cwN;                   // L0 only: scalar-x weights
    const void* Wihp = layer ? Wih1 : Wih0;
    const void* Whhp = layer ? Whh1 : Whh0;
    const void* bihp = layer ? bih1 : bih0;
    const void* bhhp = layer ? bhh1 : bhh0;
    const int hb0 = 32 * (tau >> 1) + 8 * hp + 4 * (tau & 1);
    #pragma unroll
    for (int g = 0; g < 3; ++g){
        const float sc = (g == 2) ? gsc2 : gsc0;
        const int grow = g * 64 + 32 * (tau >> 1) + 8 * (am >> 2) + 4 * (tau & 1) + (am & 3);
        if (layer == 0){
            wA[g][0] = mk_frag(Whhp, grow, 8 * hp,      f32, sc);
            wA[g][1] = mk_frag(Whhp, grow, 32 + 8 * hp, f32, sc);
        } else {
            wA[g][0] = mk_frag(Wihp, grow, 8 * hp,      f32, sc);
            wA[g][1] = mk_frag(Wihp, grow, 32 + 8 * hp, f32, sc);
            wH[g][0] = mk_frag(Whhp, grow, 8 * hp,      f32, sc);
            wH[g][1] = mk_frag(Whhp, grow, 32 + 8 * hp, f32, sc);
        }
    }
    #pragma unroll
    for (int r = 0; r < 4; ++r){
        const int hc = hb0 + r;
        cbR[r]  = (ld_any(bihp, hc, f32)      + ld_any(bhhp, hc, f32))      * gsc0;
        cbZ[r]  = (ld_any(bihp, 64 + hc, f32) + ld_any(bhhp, 64 + hc, f32)) * gsc0;
        cbNx[r] = ld_any(bihp, 128 + hc, f32) * gsc2;
        cbNh[r] = ld_any(bhhp, 128 + hc, f32) * gsc2;
        if (layer == 0){
            cwR[r] = ld_any(Wih0, hc, f32)       * gsc0;
            cwZ[r] = ld_any(Wih0, 64 + hc, f32)  * gsc0;
            cwN[r] = ld_any(Wih0, 128 + hc, f32) * gsc2;
        }
    }

    f32x4 hS = {0.f, 0.f, 0.f, 0.f};       // f32-carried h, this wave's quarter

    __syncthreads();

    for (int t = 0; t < T_LEN; ++t){
        if (layer == 0){
            // ---- layer 0, step t: hA(t) = GRU0(x(t), hA(t-1)) ----
            const int p = t & 1, pr = p ^ 1;
            ui2 q0 = hAq[grp][pr][0][l], q1 = hAq[grp][pr][1][l];
            ui2 q2 = hAq[grp][pr][2][l], q3 = hAq[grp][pr][3][l];
            ui4 u0 = {q0[0], q0[1], q1[0], q1[1]};
            ui4 u1 = {q2[0], q2[1], q3[0], q3[1]};
            bf16x8 B0 = __builtin_bit_cast(bf16x8, u0);   // k 8hp..8hp+7
            bf16x8 B1 = __builtin_bit_cast(bf16x8, u1);   // k 32+8hp..+7
            const float xb = xbuf[grp][b * XPAD + t];
            f32x4 aR, aZ, aX, aN;
            #pragma unroll
            for (int r = 0; r < 4; ++r){
                aR[r] = fmaf(xb, cwR[r], cbR[r]);
                aZ[r] = fmaf(xb, cwZ[r], cbZ[r]);
                aX[r] = fmaf(xb, cwN[r], cbNx[r]);
            }
            aR = mfma16(wA[0][0], B0, aR); aR = mfma16(wA[0][1], B1, aR);
            aZ = mfma16(wA[1][0], B0, aZ); aZ = mfma16(wA[1][1], B1, aZ);
            aN = mfma16(wA[2][0], B0, cbNh); aN = mfma16(wA[2][1], B1, aN);
            #pragma unroll
            for (int r = 0; r < 4; ++r){
                float rg = sigm2(aR[r]);
                float zg = sigm2(aZ[r]);
                float ng = tanh2(aX[r] + rg * aN[r]);
                hS[r] = ng + zg * (hS[r] - ng);
            }
            ui2 own = { cvtpk(hS[0], hS[1]), cvtpk(hS[2], hS[3]) };
            hAq[grp][p][tau][l] = own;
        } else if (t > 0){
            // ---- layer 1, step t-1: hB(t-1) = GRU1(hA(t-1), hB(t-2)) ----
            const int pa = (t - 1) & 1, pb = pa ^ 1;
            ui2 a0 = hAq[grp][pa][0][l], a1 = hAq[grp][pa][1][l];
            ui2 a2 = hAq[grp][pa][2][l], a3 = hAq[grp][pa][3][l];
            ui2 c0 = hBq[grp][pb][0][l], c1 = hBq[grp][pb][1][l];
            ui2 c2 = hBq[grp][pb][2][l], c3 = hBq[grp][pb][3][l];
            ui4 ua0 = {a0[0], a0[1], a1[0], a1[1]};
            ui4 ua1 = {a2[0], a2[1], a3[0], a3[1]};
            ui4 ub0 = {c0[0], c0[1], c1[0], c1[1]};
            ui4 ub1 = {c2[0], c2[1], c3[0], c3[1]};
            bf16x8 gA0 = __builtin_bit_cast(bf16x8, ua0);
            bf16x8 gA1 = __builtin_bit_cast(bf16x8, ua1);
            bf16x8 B0  = __builtin_bit_cast(bf16x8, ub0);
            bf16x8 B1  = __builtin_bit_cast(bf16x8, ub1);
            f32x4 aR, aZ, aX, aN;
            aR = mfma16(wA[0][0], gA0, cbR);  aR = mfma16(wA[0][1], gA1, aR);
            aR = mfma16(wH[0][0], B0,  aR);   aR = mfma16(wH[0][1], B1,  aR);
            aZ = mfma16(wA[1][0], gA0, cbZ);  aZ = mfma16(wA[1][1], gA1, aZ);
            aZ = mfma16(wH[1][0], B0,  aZ);   aZ = mfma16(wH[1][1], B1,  aZ);
            aX = mfma16(wA[2][0], gA0, cbNx); aX = mfma16(wA[2][1], gA1, aX);
            aN = mfma16(wH[2][0], B0,  cbNh); aN = mfma16(wH[2][1], B1,  aN);
            #pragma unroll
            for (int r = 0; r < 4; ++r){
                float rg = sigm2(aR[r]);
                float zg = sigm2(aZ[r]);
                float ng = tanh2(aX[r] + rg * aN[r]);
                hS[r] = ng + zg * (hS[r] - ng);
            }
            ui2 own = { cvtpk(hS[0], hS[1]), cvtpk(hS[2], hS[3]) };
            hBq[grp][pa][tau][l] = own;
        }
        __syncthreads();
    }

    // Epilogue: L1 waves compute hB(511) from hA(511) (parity 1) and
    // hB(510) (parity 0), then fold the FC dot-product in registers.
    if (layer == 1){
        ui2 a0 = hAq[grp][1][0][l], a1 = hAq[grp][1][1][l];
        ui2 a2 = hAq[grp][1][2][l], a3 = hAq[grp][1][3][l];
        ui2 c0 = hBq[grp][0][0][l], c1 = hBq[grp][0][1][l];
        ui2 c2 = hBq[grp][0][2][l], c3 = hBq[grp][0][3][l];
        ui4 ua0 = {a0[0], a0[1], a1[0], a1[1]};
        ui4 ua1 = {a2[0], a2[1], a3[0], a3[1]};
        ui4 ub0 = {c0[0], c0[1], c1[0], c1[1]};
        ui4 ub1 = {c2[0], c2[1], c3[0], c3[1]};
        bf16x8 gA0 = __builtin_bit_cast(bf16x8, ua0);
        bf16x8 gA1 = __builtin_bit_cast(bf16x8, ua1);
        bf16x8 B0  = __builtin_bit_cast(bf16x8, ub0);
        bf16x8 B1  = __builtin_bit_cast(bf16x8, ub1);
        f32x4 aR, aZ, aX, aN;
        aR = mfma16(wA[0][0], gA0, cbR);  aR = mfma16(wA[0][1], gA1, aR);
        aR = mfma16(wH[0][0], B0,  aR);   aR = mfma16(wH[0][1], B1,  aR);
        aZ = mfma16(wA[1][0], gA0, cbZ);  aZ = mfma16(wA[1][1], gA1, aZ);
        aZ = mfma16(wH[1][0], B0,  aZ);   aZ = mfma16(wH[1][1], B1,  aZ);
        aX = mfma16(wA[2][0], gA0, cbNx); aX = mfma16(wA[2][1], gA1, aX);
        aN = mfma16(wH[2][0], B0,  cbNh); aN = mfma16(wH[2][1], B1,  aN);
        float part = 0.0f;
        #pragma unroll
        for (int r = 0; r < 4; ++r){
            float rg = sigm2(aR[r]);
            float zg = sigm2(aZ[r]);
            float ng = tanh2(aX[r] + rg * aN[r]);
            float hf = ng + zg * (hS[r] - ng);
            part = fmaf(ld_any(Wfc, hb0 + r, f32), hf, part);
        }
        part += __shfl_xor(part, 16);      // reduce across hp
        part += __shfl_xor(part, 32);
        if (l < 16) fcb[grp][tau][b] = part;
    }
    __syncthreads();

    if (wv == 0 && l < 16){
        float s = fcb[grp][0][b] + fcb[grp][1][b] + fcb[grp][2][b] + fcb[grp][3][b]
                + ld_any(bfc, 0, f32);
        if (f32) ((float*)outv)[row0 + b] = s;
        else     ((ushort_t*)outv)[row0 + b] = f2bf(s);
    }
}

extern "C" void kernel_launch(void* const* d_in, const int* in_sizes, int n_in,
                              void* d_out, int out_size, void* d_ws, size_t ws_size,
                              hipStream_t stream)
{
    (void)in_sizes; (void)n_in; (void)d_ws; (void)ws_size;
    const int B = out_size;               // O = 1 -> out_size == batch
    const int nblk = B / (16 * GPB);      // 2048/32 = 64 blocks, 16 waves each
    gru_fused<<<nblk, 1024, 0, stream>>>(
        d_in[0],
        d_in[1], d_in[2], d_in[3], d_in[4],
        d_in[5], d_in[6], d_in[7], d_in[8],
        d_in[9], d_in[10],
        d_out);
}

// Round 12
// 352.352 us; speedup vs baseline: 1.6695x; 1.5677x over previous
//
#include <hip/hip_runtime.h>

// UniversalGRU: 2-layer GRU (B=2048, T=512, D=1, H=64) + FC(64->1).
// R19 = R12 (best measured: 296us; 8 waves, tau-single split, one
// barrier/step) + step micro-surgery. R13-R18 bracketed R12 from every
// structural direction (fewer barriers, more waves, flags, in-wave ILP,
// producer/consumer) -- all regressed; wall = 512 x per-block interval,
// so only shortening R12's step helps. R19 cuts:
//  1) L0 x-terms via MFMA (BX = [x,0..] at k=0, biases stay f32 C-in):
//     -12 VALU fma, +3 MFMA on the idle matrix pipe, issued while the
//     h ds_reads are in flight (validated correct in R16's L0).
//  2) t-loop unrolled x2 -> compile-time parity, static LDS offsets.
//  3) R-gate MFMAs ordered first so the exp->rcp chain for rg (feeds ng,
//     the longest serial path) starts under the Z/N MFMA issue.
// Everything else bit-identical to R12. 128 blocks x 512 threads.

#define T_LEN 512
#define BROWS 16
#define XPAD  513
#define LOG2E 1.44269504088896f

typedef float          f32x4 __attribute__((ext_vector_type(4)));
typedef __bf16         bf16x8 __attribute__((ext_vector_type(8)));
typedef unsigned short us8   __attribute__((ext_vector_type(8)));
typedef unsigned int   ui4   __attribute__((ext_vector_type(4)));
typedef unsigned int   ui2   __attribute__((ext_vector_type(2)));
typedef unsigned short ushort_t;

__device__ __forceinline__ float bf2f(ushort_t b){
    unsigned int u = ((unsigned int)b) << 16;
    return __uint_as_float(u);
}
__device__ __forceinline__ ushort_t f2bf(float f){
    unsigned int u = __float_as_uint(f);
    u = (u + 0x7FFFu + ((u >> 16) & 1u)) >> 16;   // RNE
    return (ushort_t)u;
}
__device__ __forceinline__ float ld_any(const void* p, int i, bool f32){
    return f32 ? ((const float*)p)[i] : bf2f(((const ushort_t*)p)[i]);
}
__device__ __forceinline__ float exp2_fast(float x){
#if __has_builtin(__builtin_amdgcn_exp2f)
    return __builtin_amdgcn_exp2f(x);          // v_exp_f32 (2^x)
#else
    return __expf(0.6931471805599453f * x);
#endif
}
__device__ __forceinline__ float rcp_fast(float x){
#if __has_builtin(__builtin_amdgcn_rcpf)
    return __builtin_amdgcn_rcpf(x);           // v_rcp_f32
#else
    return __fdividef(1.0f, x);
#endif
}
// sigma(x) with pre-scaled argument t = log2e * x
__device__ __forceinline__ float sigm2(float t){
    return rcp_fast(1.0f + exp2_fast(-t));
}
// tanh(y) with pre-scaled argument t = 2*log2e * y
__device__ __forceinline__ float tanh2(float t){
    return fmaf(-2.0f, rcp_fast(exp2_fast(t) + 1.0f), 1.0f);
}
__device__ __forceinline__ f32x4 mfma16(bf16x8 a, bf16x8 b, f32x4 c){
    return __builtin_amdgcn_mfma_f32_16x16x32_bf16(a, b, c, 0, 0, 0);
}
// packed f32x2 -> bf16x2 (RNE) in one instruction
__device__ __forceinline__ unsigned int cvtpk(float lo, float hi){
    unsigned int r;
    asm("v_cvt_pk_bf16_f32 %0, %1, %2" : "=v"(r) : "v"(lo), "v"(hi));
    return r;
}
// A-fragment: 8 contiguous k's of W[n][k], pre-scaled then bf16-rounded.
__device__ __forceinline__ bf16x8 mk_frag(const void* W, int n, int kb, bool f32, float sc){
    us8 tmp;
    #pragma unroll
    for (int j = 0; j < 8; ++j){
        float v = f32 ? ((const float*)W)[n * 64 + kb + j]
                      : bf2f(((const ushort_t*)W)[n * 64 + kb + j]);
        tmp[j] = f2bf(v * sc);
    }
    return __builtin_bit_cast(bf16x8, tmp);
}

// ---- L0 step (parity P compile-time): hA(T) = GRU0(x(T), hA(T-1)) ----
#define L0_BODY(P, T) do {                                                  \
    ui2 q0 = hAq[1-(P)][0][l], q1 = hAq[1-(P)][1][l];                       \
    ui2 q2 = hAq[1-(P)][2][l], q3 = hAq[1-(P)][3][l];                       \
    const float xb = xbuf[b * XPAD + (T)];                                  \
    unsigned int bxw = (hp == 0) ? cvtpk(xb, 0.0f) : 0u;                    \
    ui4 bxu = {bxw, 0u, 0u, 0u};                                            \
    bf16x8 BX = __builtin_bit_cast(bf16x8, bxu);                            \
    f32x4 aR = mfma16(wx[0], BX, cbR);     /* x-terms on matrix pipe */     \
    f32x4 aZ = mfma16(wx[1], BX, cbZ);                                      \
    f32x4 aX = mfma16(wx[2], BX, cbNx);                                     \
    ui4 u0 = {q0[0], q0[1], q1[0], q1[1]};                                  \
    ui4 u1 = {q2[0], q2[1], q3[0], q3[1]};                                  \
    bf16x8 B0 = __builtin_bit_cast(bf16x8, u0);   /* k 8hp..8hp+7   */      \
    bf16x8 B1 = __builtin_bit_cast(bf16x8, u1);   /* k 32+8hp..+7   */      \
    aR = mfma16(wA[0][0], B0, aR); aR = mfma16(wA[0][1], B1, aR);           \
    aZ = mfma16(wA[1][0], B0, aZ); aZ = mfma16(wA[1][1], B1, aZ);           \
    f32x4 aN = mfma16(wA[2][0], B0, cbNh);                                  \
    aN = mfma16(wA[2][1], B1, aN);                                          \
    _Pragma("unroll")                                                       \
    for (int r = 0; r < 4; ++r){                                            \
        float rg = sigm2(aR[r]);                                            \
        float zg = sigm2(aZ[r]);                                            \
        float ng = tanh2(aX[r] + rg * aN[r]);                               \
        hS[r] = ng + zg * (hS[r] - ng);                                     \
    }                                                                       \
    ui2 own = { cvtpk(hS[0], hS[1]), cvtpk(hS[2], hS[3]) };                 \
    hAq[(P)][tau][l] = own;                                                 \
} while (0)

// ---- L1 step (parity PA compile-time): hB = GRU1(hA[PA], hB[1-PA]) ----
#define L1_BODY(PA) do {                                                    \
    ui2 a0 = hAq[(PA)][0][l], a1 = hAq[(PA)][1][l];                         \
    ui2 a2 = hAq[(PA)][2][l], a3 = hAq[(PA)][3][l];                         \
    ui2 c0 = hBq[1-(PA)][0][l], c1 = hBq[1-(PA)][1][l];                     \
    ui2 c2 = hBq[1-(PA)][2][l], c3 = hBq[1-(PA)][3][l];                     \
    ui4 ua0 = {a0[0], a0[1], a1[0], a1[1]};                                 \
    ui4 ua1 = {a2[0], a2[1], a3[0], a3[1]};                                 \
    ui4 ub0 = {c0[0], c0[1], c1[0], c1[1]};                                 \
    ui4 ub1 = {c2[0], c2[1], c3[0], c3[1]};                                 \
    bf16x8 gA0 = __builtin_bit_cast(bf16x8, ua0);                           \
    bf16x8 gA1 = __builtin_bit_cast(bf16x8, ua1);                           \
    bf16x8 B0  = __builtin_bit_cast(bf16x8, ub0);                           \
    bf16x8 B1  = __builtin_bit_cast(bf16x8, ub1);                           \
    f32x4 aR, aZ, aX, aN;                                                   \
    aR = mfma16(wA[0][0], gA0, cbR);  aR = mfma16(wA[0][1], gA1, aR);       \
    aR = mfma16(wH[0][0], B0,  aR);   aR = mfma16(wH[0][1], B1,  aR);       \
    aZ = mfma16(wA[1][0], gA0, cbZ);  aZ = mfma16(wA[1][1], gA1, aZ);       \
    aZ = mfma16(wH[1][0], B0,  aZ);   aZ = mfma16(wH[1][1], B1,  aZ);       \
    aX = mfma16(wA[2][0], gA0, cbNx); aX = mfma16(wA[2][1], gA1, aX);       \
    aN = mfma16(wH[2][0], B0,  cbNh); aN = mfma16(wH[2][1], B1,  aN);       \
    _Pragma("unroll")                                                       \
    for (int r = 0; r < 4; ++r){                                            \
        float rg = sigm2(aR[r]);                                            \
        float zg = sigm2(aZ[r]);                                            \
        float ng = tanh2(aX[r] + rg * aN[r]);                               \
        hS[r] = ng + zg * (hS[r] - ng);                                     \
    }                                                                       \
    ui2 own = { cvtpk(hS[0], hS[1]), cvtpk(hS[2], hS[3]) };                 \
    hBq[(PA)][tau][l] = own;                                                \
} while (0)

__global__ __launch_bounds__(512, 2) void gru_fused(
    const void* __restrict__ xv,
    const void* __restrict__ Wih0, const void* __restrict__ Whh0,
    const void* __restrict__ bih0, const void* __restrict__ bhh0,
    const void* __restrict__ Wih1, const void* __restrict__ Whh1,
    const void* __restrict__ bih1, const void* __restrict__ bhh1,
    const void* __restrict__ Wfc,  const void* __restrict__ bfc,
    void* __restrict__ outv)
{
    __shared__ float xbuf[BROWS * XPAD];   // staged x, f32, padded stride
    // h exchange: [parity][quarter tau][lane], ui2 = 4 bf16 in frag layout.
    __shared__ ui2   hAq[2][4][64];
    __shared__ ui2   hBq[2][4][64];
    __shared__ float fcb[4][16];           // FC cross-wave partials

    const int tid   = threadIdx.x;
    const int wv    = tid >> 6;            // 0..7
    const int layer = wv >> 2;             // 0 = GRU0 waves, 1 = GRU1 waves
    const int tau   = wv & 3;              // weight tile this wave owns
    const int l  = tid & 63;
    const int b  = l & 15;                 // batch row (MFMA D column)
    const int hp = l >> 4;                 // k-group (MFMA D row block)
    const int am = l & 15;                 // A-operand row this lane loads
    const long row0 = (long)blockIdx.x * BROWS;

    // dtype detection (uniform): fp32 misread as bf16 -> mantissa-noise
    // exponents in even ushort slots; true bf16 never exceeds exp 150.
    bool f32 = false;
    {
        const ushort_t* xs = (const ushort_t*)xv;
        for (int j = 0; j < 64; ++j){
            int e = (xs[2 * j] >> 7) & 0xFF;
            if (e > 150) f32 = true;
        }
    }

    // zero exchange buffers (h(-1) = 0, h(-2) = 0; both parities)
    {
        ui2 z = {0u, 0u};
        ui2* pa = &hAq[0][0][0];
        ui2* pb = &hBq[0][0][0];
        for (int k = tid; k < 2 * 4 * 64; k += 512){ pa[k] = z; pb[k] = z; }
    }
    // stage x: 16 rows x 512, all 8 waves cooperate, convert to f32
    if (f32){
        for (int idx = tid; idx < BROWS * (T_LEN / 4); idx += 512){
            const int r = idx >> 7, sg = idx & 127;
            f32x4 v = ((const f32x4*)((const float*)xv + (row0 + r) * T_LEN))[sg];
            #pragma unroll
            for (int j = 0; j < 4; ++j) xbuf[r * XPAD + sg * 4 + j] = v[j];
        }
    } else {
        for (int idx = tid; idx < BROWS * (T_LEN / 8); idx += 512){
            const int r = idx >> 6, sg = idx & 63;
            us8 v = ((const us8*)((const ushort_t*)xv + (row0 + r) * T_LEN))[sg];
            #pragma unroll
            for (int j = 0; j < 8; ++j) xbuf[r * XPAD + sg * 8 + j] = bf2f(v[j]);
        }
    }

    const float gsc0 = LOG2E, gsc2 = 2.0f * LOG2E;

    // ---- weight / bias setup (per wave role) ----
    // Permuted gate row for tile tau:
    //   grow(g) = g*64 + 32*(tau>>1) + 8*(am>>2) + 4*(tau&1) + (am&3)
    // Lane's D outputs land at h-col hc(r) = hb0 + r,
    //   hb0 = 32*(tau>>1) + 8*hp + 4*(tau&1)  -- the ui2 quarter published.
    bf16x8 wA[3][2];                       // L0: Whh0. L1: Wih1.
    bf16x8 wH[3][2];                       // L1 only: Whh1.
    bf16x8 wx[3];                          // L0 only: x-weight frag (k0 = Wx)
    f32x4 cbR, cbZ, cbNx, cbNh;
    const void* Wihp = layer ? Wih1 : Wih0;
    const void* Whhp = layer ? Whh1 : Whh0;
    const void* bihp = layer ? bih1 : bih0;
    const void* bhhp = layer ? bhh1 : bhh0;
    const int hb0 = 32 * (tau >> 1) + 8 * hp + 4 * (tau & 1);
    #pragma unroll
    for (int g = 0; g < 3; ++g){
        const float sc = (g == 2) ? gsc2 : gsc0;
        const int grow = g * 64 + 32 * (tau >> 1) + 8 * (am >> 2) + 4 * (tau & 1) + (am & 3);
        if (layer == 0){
            wA[g][0] = mk_frag(Whhp, grow, 8 * hp,      f32, sc);
            wA[g][1] = mk_frag(Whhp, grow, 32 + 8 * hp, f32, sc);
            us8 t8 = {0, 0, 0, 0, 0, 0, 0, 0};
            if (hp == 0) t8[0] = f2bf(ld_any(Wih0, grow, f32) * sc);
            wx[g] = __builtin_bit_cast(bf16x8, t8);
        } else {
            wA[g][0] = mk_frag(Wihp, grow, 8 * hp,      f32, sc);
            wA[g][1] = mk_frag(Wihp, grow, 32 + 8 * hp, f32, sc);
            wH[g][0] = mk_frag(Whhp, grow, 8 * hp,      f32, sc);
            wH[g][1] = mk_frag(Whhp, grow, 32 + 8 * hp, f32, sc);
        }
    }
    #pragma unroll
    for (int r = 0; r < 4; ++r){
        const int hc = hb0 + r;
        cbR[r]  = (ld_any(bihp, hc, f32)      + ld_any(bhhp, hc, f32))      * gsc0;
        cbZ[r]  = (ld_any(bihp, 64 + hc, f32) + ld_any(bhhp, 64 + hc, f32)) * gsc0;
        cbNx[r] = ld_any(bihp, 128 + hc, f32) * gsc2;
        cbNh[r] = ld_any(bhhp, 128 + hc, f32) * gsc2;
    }

    f32x4 hS = {0.f, 0.f, 0.f, 0.f};       // f32-carried h, this wave's quarter

    __syncthreads();

    // Unrolled x2: compile-time parities. Even slot t=t2 (L0 writes hAq[0],
    // L1 reads hAq[1]/hBq[0], writes hBq[1]); odd slot t=t2+1 mirrored.
    for (int t2 = 0; t2 < T_LEN; t2 += 2){
        if (layer == 0){
            L0_BODY(0, t2);
        } else if (t2 > 0){
            L1_BODY(1);                    // computes hB(t2-1)
        }
        __syncthreads();
        if (layer == 0){
            L0_BODY(1, t2 + 1);
        } else {
            L1_BODY(0);                    // computes hB(t2)
        }
        __syncthreads();
    }

    // Epilogue: L1 waves compute hB(511) from hA(511) (parity 1) and
    // hB(510) (parity 0), then fold the FC dot-product in registers.
    if (layer == 1){
        ui2 a0 = hAq[1][0][l], a1 = hAq[1][1][l];
        ui2 a2 = hAq[1][2][l], a3 = hAq[1][3][l];
        ui2 c0 = hBq[0][0][l], c1 = hBq[0][1][l];
        ui2 c2 = hBq[0][2][l], c3 = hBq[0][3][l];
        ui4 ua0 = {a0[0], a0[1], a1[0], a1[1]};
        ui4 ua1 = {a2[0], a2[1], a3[0], a3[1]};
        ui4 ub0 = {c0[0], c0[1], c1[0], c1[1]};
        ui4 ub1 = {c2[0], c2[1], c3[0], c3[1]};
        bf16x8 gA0 = __builtin_bit_cast(bf16x8, ua0);
        bf16x8 gA1 = __builtin_bit_cast(bf16x8, ua1);
        bf16x8 B0  = __builtin_bit_cast(bf16x8, ub0);
        bf16x8 B1  = __builtin_bit_cast(bf16x8, ub1);
        f32x4 aR, aZ, aX, aN;
        aR = mfma16(wA[0][0], gA0, cbR);  aR = mfma16(wA[0][1], gA1, aR);
        aR = mfma16(wH[0][0], B0,  aR);   aR = mfma16(wH[0][1], B1,  aR);
        aZ = mfma16(wA[1][0], gA0, cbZ);  aZ = mfma16(wA[1][1], gA1, aZ);
        aZ = mfma16(wH[1][0], B0,  aZ);   aZ = mfma16(wH[1][1], B1,  aZ);
        aX = mfma16(wA[2][0], gA0, cbNx); aX = mfma16(wA[2][1], gA1, aX);
        aN = mfma16(wH[2][0], B0,  cbNh); aN = mfma16(wH[2][1], B1,  aN);
        float part = 0.0f;
        #pragma unroll
        for (int r = 0; r < 4; ++r){
            float rg = sigm2(aR[r]);
            float zg = sigm2(aZ[r]);
            float ng = tanh2(aX[r] + rg * aN[r]);
            float hf = ng + zg * (hS[r] - ng);
            part = fmaf(ld_any(Wfc, hb0 + r, f32), hf, part);
        }
        part += __shfl_xor(part, 16);      // reduce across hp
        part += __shfl_xor(part, 32);
        if (l < 16) fcb[tau][b] = part;
    }
    __syncthreads();

    if (wv == 0 && l < 16){
        float s = fcb[0][b] + fcb[1][b] + fcb[2][b] + fcb[3][b]
                + ld_any(bfc, 0, f32);
        if (f32) ((float*)outv)[row0 + b] = s;
        else     ((ushort_t*)outv)[row0 + b] = f2bf(s);
    }
}

extern "C" void kernel_launch(void* const* d_in, const int* in_sizes, int n_in,
                              void* d_out, int out_size, void* d_ws, size_t ws_size,
                              hipStream_t stream)
{
    (void)in_sizes; (void)n_in; (void)d_ws; (void)ws_size;
    const int B = out_size;               // O = 1 -> out_size == batch
    const int nblk = B / BROWS;           // 2048/16 = 128 blocks, 8 waves each
    gru_fused<<<nblk, 512, 0, stream>>>(
        d_in[0],
        d_in[1], d_in[2], d_in[3], d_in[4],
        d_in[5], d_in[6], d_in[7], d_in[8],
        d_in[9], d_in[10],
        d_out);
}